// Round 11
// baseline (264.256 us; speedup 1.0000x reference)
//
#include <hip/hip_runtime.h>
#include <stdint.h>

// LSTMModel via MFMA (f16 weights/h, fp32 acc/c): 2-layer LSTM (H1=50, H2=64),
// B=2048, T=512 + FC 64->32->16->1.
//
// Round 11 = Round 10 with the cvt_pkrtz type fix (builtin returns __fp16x2;
// bit-cast to uint32_t and ds_write_b32 it).
//  - K-PERMUTED H LAYOUT -> PACKED CONFLICT-FREE WRITES:
//    H position perm: pos(u=8W+4tl+g) = 8W+2g+tl. A-matrices' k-columns are
//    permuted identically at staging (u_k = (k&~7)|((k&1)<<2)|((k&7)>>1)), so
//    the MFMA contraction is invariant. The xor-8 lane pair (tl=0/1, same g)
//    holds ADJACENT positions: pack via dpp row_ror:8 + v_cvt_pkrtz_f16_f32,
//    lanes nn<8 do ONE ds_write_b32 at byte col*144 + 16W + 4g -> bank
//    4col+g+4W: all 32 writer lanes hit distinct banks. Replaces 64x 2B
//    writes/wave (4-way same-dword pileup) with 32x 4B clean.
//  - Wave 7 (all-pad L1) skips its entire body (only barriers).
// Structure (R9): 256 blocks x 1024 threads, class split (waves 0-7 L1 duty,
// 8-15 L2 duty), exp2 pre-scaled gates, setprio around L2 MFMA, skewed
// pipeline (layer2 one step behind), ONE barrier/step, Nb=8, x prefetch.
// Invariant: h1(tau) in H1[(tau+1)&1], h2(tau) in H2[(tau+1)&1]. At iter t
// (cur=t&1): read h1(t-1)=H1[cur], h2(t-2)=H2[cur^1]; write h1(t)->H1[cur^1]
// (L1 waves), h2(t-1)->H2[cur] (L2 waves). t=0 forces c2=0 (h2(-1)=0).

typedef _Float16 f16x8 __attribute__((ext_vector_type(8)));
typedef float f32x4 __attribute__((ext_vector_type(4)));

#define TLEN 512
#define STG 0            // 256x64 f16 staging = 32768 B (later: FC scratch)
#define H1OFF 32768      // 2 bufs x 8 rows x 144 B = 2304
#define HSTR 144
#define HBUF 1152        // one buffer = 8*144
#define H2OFF 35088      // 32768 + 2304 + 16 (bank skew)
#define LDSB 37392

#define NLOG2E -1.4426950408889634f
#define TLOG2E  2.8853900817779268f   // +2*log2e

__device__ __forceinline__ float rcpf_(float x) {
#if __has_builtin(__builtin_amdgcn_rcpf)
  return __builtin_amdgcn_rcpf(x);
#else
  return __fdividef(1.0f, x);
#endif
}
__device__ __forceinline__ float exp2_(float x) {
#if __has_builtin(__builtin_amdgcn_exp2f)
  return __builtin_amdgcn_exp2f(x);
#else
  return exp2f(x);
#endif
}
// pack two f32 -> one dword of 2xf16 (RTZ)
__device__ __forceinline__ uint32_t pkf16(float lo, float hi) {
  auto v = __builtin_amdgcn_cvt_pkrtz(lo, hi);   // __fp16 ext_vector_type(2)
  return __builtin_bit_cast(uint32_t, v);
}

// lanes with (lane mod 16) >= 8 get dv from lane^8; lanes nn<8 keep av.
__device__ __forceinline__ float dppsel(float av, float dv) {
  return __int_as_float(__builtin_amdgcn_update_dpp(
      __float_as_int(av), __float_as_int(dv),
      0x128 /*row_ror:8*/, 0xF /*row_mask*/, 0xC /*bank_mask*/, false));
}
// every lane receives the value from lane^8 (within its 16-lane row)
__device__ __forceinline__ float dppror8(float v) {
  return __int_as_float(__builtin_amdgcn_update_dpp(
      0, __float_as_int(v), 0x128 /*row_ror:8*/, 0xF, 0xF, true));
}

#define MFMA16(A, B, C) __builtin_amdgcn_mfma_f32_16x16x32_f16(A, B, C, 0, 0, 0)

// staging k-perm: position k holds unit u_k
__device__ __forceinline__ int kperm(int k) {
  return (k & ~7) | ((k & 1) << 2) | ((k & 7) >> 1);
}

__global__ __launch_bounds__(1024, 1)
void lstm_mfma(const float* __restrict__ x,
               const float* __restrict__ w_ih1, const float* __restrict__ w_hh1,
               const float* __restrict__ b_ih1, const float* __restrict__ b_hh1,
               const float* __restrict__ w_ih2, const float* __restrict__ w_hh2,
               const float* __restrict__ b_ih2, const float* __restrict__ b_hh2,
               const float* __restrict__ fc1_w, const float* __restrict__ fc1_b,
               const float* __restrict__ fc2_w, const float* __restrict__ fc2_b,
               const float* __restrict__ fc3_w, const float* __restrict__ fc3_b,
               float* __restrict__ out)
{
  __shared__ __align__(16) char smem[LDSB];
  const int tid = threadIdx.x;
  const int wv = tid >> 6, ln = tid & 63;
  const int nn = ln & 15, g = ln >> 4;
  const bool isL2 = (wv >= 8);
  const int W = isL2 ? (wv - 8) : wv;       // class-local wave index (0..7)
  const int tl = nn >> 3;                   // which tile this lane updates
  const int col = nn & 7;                   // batch col
  const int uA = W * 8 + tl * 4 + g;        // this lane's update unit
  const bool deadWave = (wv == 7);          // all-pad L1 wave: barriers only

  _Float16* stg = (_Float16*)(smem + STG);
  // gate-row scales: i,f,o -> -log2e ; g -> +2log2e
  const float SCQ[4] = {NLOG2E, NLOG2E, TLOG2E, NLOG2E};

  // F0: L1 = whh1 tiles / L2 = wih2 tiles.  F1: L2 = whh2 tiles (L1: unused).
  f16x8 F0[2][2], F1[2][2];
#pragma unroll
  for (int t2 = 0; t2 < 2; ++t2)
#pragma unroll
    for (int kf = 0; kf < 2; ++kf) F1[t2][kf] = (f16x8)(_Float16)0.f;

  // ---- phase A: stage whh1 (rows 4v+q interleave; k-cols permuted; scaled) ----
  for (int idx = tid; idx < 16384; idx += 1024) {
    int R = idx >> 6, k = idx & 63, v = R >> 2, q = R & 3, uk = kperm(k);
    stg[idx] = (_Float16)((v < 50 && uk < 50) ? w_hh1[(q * 50 + v) * 50 + uk] * SCQ[q] : 0.f);
  }
  __syncthreads();
  if (!isL2) {
#pragma unroll
    for (int t2 = 0; t2 < 2; ++t2) {
      int base = ((W * 2 + t2) * 16 + nn) * 128 + g * 16;
      F0[t2][0] = *(const f16x8*)(smem + STG + base);
      F0[t2][1] = *(const f16x8*)(smem + STG + base + 64);
    }
  }
  __syncthreads();
  // ---- phase B: stage wih2 (k over h1 positions) ----
  for (int idx = tid; idx < 16384; idx += 1024) {
    int R = idx >> 6, k = idx & 63, v = R >> 2, q = R & 3, uk = kperm(k);
    stg[idx] = (_Float16)((uk < 50) ? w_ih2[(q * 64 + v) * 50 + uk] * SCQ[q] : 0.f);
  }
  __syncthreads();
  if (isL2) {
#pragma unroll
    for (int t2 = 0; t2 < 2; ++t2) {
      int base = ((W * 2 + t2) * 16 + nn) * 128 + g * 16;
      F0[t2][0] = *(const f16x8*)(smem + STG + base);
      F0[t2][1] = *(const f16x8*)(smem + STG + base + 64);
    }
  }
  __syncthreads();
  // ---- phase C: stage whh2 (k over h2 positions) + zero H buffers ----
  for (int idx = tid; idx < 16384; idx += 1024) {
    int R = idx >> 6, k = idx & 63, v = R >> 2, q = R & 3, uk = kperm(k);
    stg[idx] = (_Float16)(w_hh2[(q * 64 + v) * 64 + uk] * SCQ[q]);
  }
  for (int i = tid; i < 1156; i += 1024) ((uint32_t*)(smem + H1OFF))[i] = 0;
  __syncthreads();
  if (isL2) {
#pragma unroll
    for (int t2 = 0; t2 < 2; ++t2) {
      int base = ((W * 2 + t2) * 16 + nn) * 128 + g * 16;
      F1[t2][0] = *(const f16x8*)(smem + STG + base);
      F1[t2][1] = *(const f16x8*)(smem + STG + base + 64);
    }
  }
  __syncthreads();

  // ---- per-lane C-seed constants (scaled): tile t2 unit u = 8W+4*t2+g ----
  float w1c[2][4], b1c[2][4];
#pragma unroll
  for (int t2 = 0; t2 < 2; ++t2) {
    int u = W * 8 + t2 * 4 + g;
#pragma unroll
    for (int q = 0; q < 4; ++q) {
      if (!isL2) {
        bool r1 = (u < 50);
        w1c[t2][q] = r1 ? w_ih1[q * 50 + u] * SCQ[q] : 0.f;
        b1c[t2][q] = r1 ? (b_ih1[q * 50 + u] + b_hh1[q * 50 + u]) * SCQ[q] : 0.f;
      } else {
        w1c[t2][q] = 0.f;
        b1c[t2][q] = (b_ih2[q * 64 + u] + b_hh2[q * 64 + u]) * SCQ[q];
      }
    }
  }
  const bool l1mfma = (!isL2) && (wv < 7);

  const float* xp = x + (blockIdx.x * 8 + col) * TLEN;

  // packed write pointers (only lanes tl==0 write): dword at col*HSTR + 16W + 4g
  // L1: h1(t) -> H1[cur^1] ; L2: h2(t-1) -> H2[cur]
  uint32_t *wp0, *wp1;  // for cur=0 / cur=1
  if (!isL2) {
    wp0 = (uint32_t*)(smem + H1OFF + HBUF + col * HSTR + W * 16 + g * 4);
    wp1 = (uint32_t*)(smem + H1OFF +    0 + col * HSTR + W * 16 + g * 4);
  } else {
    wp0 = (uint32_t*)(smem + H2OFF +    0 + col * HSTR + W * 16 + g * 4);
    wp1 = (uint32_t*)(smem + H2OFF + HBUF + col * HSTR + W * 16 + g * 4);
  }

  // aliased read bases (all lanes read real col nn&7 -> broadcast pairs)
  const char* const h1b = smem + H1OFF + col * HSTR;
  const char* const h2b = smem + H2OFF + col * HSTR;

  float cs = 0.f;                 // c1 (L1 waves) or c2 (L2 waves)

  float4 xa = {0.f,0.f,0.f,0.f}, xb = {0.f,0.f,0.f,0.f};
  if (!isL2 && !deadWave) { xa = *(const float4*)&xp[0]; xb = *(const float4*)&xp[4]; }

  for (int tb = 0; tb < TLEN; tb += 8) {
    float4 na = {0.f,0.f,0.f,0.f}, nb = {0.f,0.f,0.f,0.f};
    if (!isL2 && !deadWave && tb + 8 < TLEN) {
      na = *(const float4*)&xp[tb + 8];
      nb = *(const float4*)&xp[tb + 12];
    }
#pragma unroll
    for (int k = 0; k < 8; ++k) {
      const int cur = k & 1;
      const bool first = (tb == 0) && (k == 0);

      if (!deadWave) {
        const f16x8 b0 = *(const f16x8*)(h1b + cur * HBUF + g * 16);
        const f16x8 b1 = *(const f16x8*)(h1b + cur * HBUF + 64 + g * 16);

        f32x4 a0, a1;
        if (!isL2) {
          // layer-1: seed = w_ih1*x + bias (scaled), + Whh1 . h1(t-1)
          const float xv = (k < 4) ? ((const float*)&xa)[k] : ((const float*)&xb)[k - 4];
          f32x4 s0, s1;
          s0[0] = fmaf(w1c[0][0], xv, b1c[0][0]);
          s0[1] = fmaf(w1c[0][1], xv, b1c[0][1]);
          s0[2] = fmaf(w1c[0][2], xv, b1c[0][2]);
          s0[3] = fmaf(w1c[0][3], xv, b1c[0][3]);
          s1[0] = fmaf(w1c[1][0], xv, b1c[1][0]);
          s1[1] = fmaf(w1c[1][1], xv, b1c[1][1]);
          s1[2] = fmaf(w1c[1][2], xv, b1c[1][2]);
          s1[3] = fmaf(w1c[1][3], xv, b1c[1][3]);
          a0 = s0; a1 = s1;
          if (l1mfma) {
            a0 = MFMA16(F0[0][0], b0, s0);  a0 = MFMA16(F0[0][1], b1, a0);
            a1 = MFMA16(F0[1][0], b0, s1);  a1 = MFMA16(F0[1][1], b1, a1);
          }
        } else {
          // layer-2: bias-seeded, Wih2 . h1(t-1) + Whh2 . h2(t-2)
          const f16x8 q0 = *(const f16x8*)(h2b + (cur ^ 1) * HBUF + g * 16);
          const f16x8 q1 = *(const f16x8*)(h2b + (cur ^ 1) * HBUF + 64 + g * 16);
          const f32x4 s0 = {b1c[0][0], b1c[0][1], b1c[0][2], b1c[0][3]};
          const f32x4 s1 = {b1c[1][0], b1c[1][1], b1c[1][2], b1c[1][3]};
          __builtin_amdgcn_s_setprio(1);
          a0 = MFMA16(F0[0][0], b0, s0);  a0 = MFMA16(F0[0][1], b1, a0);
          a0 = MFMA16(F1[0][0], q0, a0);  a0 = MFMA16(F1[0][1], q1, a0);
          a1 = MFMA16(F0[1][0], b0, s1);  a1 = MFMA16(F0[1][1], b1, a1);
          a1 = MFMA16(F1[1][0], q0, a1);  a1 = MFMA16(F1[1][1], q1, a1);
          __builtin_amdgcn_s_setprio(0);
        }

        // half-split: lanes nn<8 take tile0 (a0), nn>=8 take tile1 from lane^8
        const float z0 = dppsel(a0[0], a1[0]);
        const float z1 = dppsel(a0[1], a1[1]);
        const float z2 = dppsel(a0[2], a1[2]);
        const float z3 = dppsel(a0[3], a1[3]);

        // gates (args pre-scaled): i,f,o sigmoid; g tanh
        const float gi = rcpf_(1.0f + exp2_(z0));
        const float gf = rcpf_(1.0f + exp2_(z1));
        const float gg = 1.0f - 2.0f * rcpf_(1.0f + exp2_(z2));
        const float go = rcpf_(1.0f + exp2_(z3));
        float c = gf * cs + gi * gg;
        if (first && isL2) c = 0.f;      // h2(-1)=0
        cs = c;
        const float h = go * (1.0f - 2.0f * rcpf_(1.0f + exp2_(TLOG2E * c)));

        // packed write: partner h from lane^8; lanes tl==0 write one dword
        const float hp = dppror8(h);
        if (tl == 0) {
          *(cur ? wp1 : wp0) = pkf16(h, hp);
        }
      }
      __syncthreads();   // the ONE barrier per step
    }
    xa = na; xb = nb;
  }

  // ---- epilogue (L2 waves): h2(511) from h1(511)=H1[0], h2(510)=H2[1] ----
  if (isL2) {
    const f16x8 b0 = *(const f16x8*)(h1b + g * 16);
    const f16x8 b1 = *(const f16x8*)(h1b + 64 + g * 16);
    const f16x8 q0 = *(const f16x8*)(h2b + HBUF + g * 16);
    const f16x8 q1 = *(const f16x8*)(h2b + HBUF + 64 + g * 16);
    const f32x4 s0 = {b1c[0][0], b1c[0][1], b1c[0][2], b1c[0][3]};
    const f32x4 s1 = {b1c[1][0], b1c[1][1], b1c[1][2], b1c[1][3]};
    f32x4 a0 = MFMA16(F0[0][0], b0, s0);  a0 = MFMA16(F0[0][1], b1, a0);
    a0 = MFMA16(F1[0][0], q0, a0);  a0 = MFMA16(F1[0][1], q1, a0);
    f32x4 a1 = MFMA16(F0[1][0], b0, s1);  a1 = MFMA16(F0[1][1], b1, a1);
    a1 = MFMA16(F1[1][0], q0, a1);  a1 = MFMA16(F1[1][1], q1, a1);
    const float z0 = dppsel(a0[0], a1[0]);
    const float z1 = dppsel(a0[1], a1[1]);
    const float z2 = dppsel(a0[2], a1[2]);
    const float z3 = dppsel(a0[3], a1[3]);
    const float gi = rcpf_(1.0f + exp2_(z0));
    const float gf = rcpf_(1.0f + exp2_(z1));
    const float gg = 1.0f - 2.0f * rcpf_(1.0f + exp2_(z2));
    const float go = rcpf_(1.0f + exp2_(z3));
    const float c = gf * cs + gi * gg;
    const float h = go * (1.0f - 2.0f * rcpf_(1.0f + exp2_(TLOG2E * c)));
    ((float*)smem)[col * 64 + uA] = h;   // fp32 h2(511): [8][64], unit-ordered
  }
  __syncthreads();

  // ---- FC head: 64 -> 32 -> 16 -> 1 ----
  float* h2f = (float*)smem;                 // [8][64]
  float* f1o = (float*)(smem + 8192);        // [8][32]
  float* f2o = (float*)(smem + 8192 + 1024); // [8][16]
  if (tid < 256) {
    int o = tid & 31, n = tid >> 5;
    float s = fc1_b[o];
#pragma unroll 8
    for (int k = 0; k < 64; ++k) s = fmaf(h2f[n * 64 + k], fc1_w[o * 64 + k], s);
    f1o[n * 32 + o] = s;
  }
  __syncthreads();
  if (tid < 128) {
    int o = tid & 15, n = tid >> 4;
    float s = fc2_b[o];
#pragma unroll 8
    for (int k = 0; k < 32; ++k) s = fmaf(f1o[n * 32 + k], fc2_w[o * 32 + k], s);
    f2o[n * 16 + o] = s;
  }
  __syncthreads();
  if (tid < 8) {
    float s = fc3_b[0];
#pragma unroll
    for (int k = 0; k < 16; ++k) s = fmaf(f2o[tid * 16 + k], fc3_w[k], s);
    out[blockIdx.x * 8 + tid] = s;
  }
}

extern "C" void kernel_launch(void* const* d_in, const int* in_sizes, int n_in,
                              void* d_out, int out_size, void* d_ws, size_t ws_size,
                              hipStream_t stream) {
  const float* x     = (const float*)d_in[0];
  const float* w_ih1 = (const float*)d_in[1];
  const float* w_hh1 = (const float*)d_in[2];
  const float* b_ih1 = (const float*)d_in[3];
  const float* b_hh1 = (const float*)d_in[4];
  const float* w_ih2 = (const float*)d_in[5];
  const float* w_hh2 = (const float*)d_in[6];
  const float* b_ih2 = (const float*)d_in[7];
  const float* b_hh2 = (const float*)d_in[8];
  const float* fc1_w = (const float*)d_in[9];
  const float* fc1_b = (const float*)d_in[10];
  const float* fc2_w = (const float*)d_in[11];
  const float* fc2_b = (const float*)d_in[12];
  const float* fc3_w = (const float*)d_in[13];
  const float* fc3_b = (const float*)d_in[14];

  hipLaunchKernelGGL(lstm_mfma, dim3(256), dim3(1024), 0, stream,
                     x, w_ih1, w_hh1, b_ih1, b_hh1,
                     w_ih2, w_hh2, b_ih2, b_hh2,
                     fc1_w, fc1_b, fc2_w, fc2_b, fc3_w, fc3_b,
                     (float*)d_out);
}